// Round 3
// baseline (141.320 us; speedup 1.0000x reference)
//
#include <hip/hip_runtime.h>
#include <math.h>

#define HW2048 (2048ull*2048ull)
typedef float f4 __attribute__((ext_vector_type(4)));
typedef float f2 __attribute__((ext_vector_type(2)));

struct BP {
  float P[4][3];   // composed 2-stage bilinear phase weights
  float D2[5];     // d^2 thresholds: L = sum(d2 >= D2[j])
  float cc[5];     // Ts exponent coefs (cc[X] = K*4^(X-2)/sig^2; cc[l] = 4*cc[l-1])
};

// ---------------- K1: img -> C1 + full pyramid p2..p5 (block-local) ---------
// Each block covers a 64x64 img tile -> 32x32 C1 -> 16x16 p2 -> 8x8 p3 ->
// 4x4 p4 -> 2x2 p5. The 2x2-average chain is exactly block-local.
__global__ __launch_bounds__(256) void downAll_k(const float* __restrict__ img,
                                                 float* __restrict__ C1,
                                                 float* __restrict__ p2,
                                                 float* __restrict__ p3,
                                                 float* __restrict__ p4,
                                                 float* __restrict__ p5) {
  __shared__ float t2[16][17];
  __shared__ float t3[8][9];
  __shared__ float t4a[4][5];
  int tx = threadIdx.x, ty = threadIdx.y;  // (16,16); grid (32,32,3)
  int X = blockIdx.x * 16 + tx;            // 0..511
  int Y = blockIdx.y * 16 + ty;            // 0..511
  int c = blockIdx.z;
  const float* ip = img + (size_t)c * HW2048 + (size_t)(4 * Y) * 2048 + 4 * X;
  f4 r0 = __builtin_nontemporal_load((const f4*)(ip));
  f4 r1 = __builtin_nontemporal_load((const f4*)(ip + 2048));
  f4 r2 = __builtin_nontemporal_load((const f4*)(ip + 4096));
  f4 r3 = __builtin_nontemporal_load((const f4*)(ip + 6144));
  float a00 = 0.25f * (r0.x + r0.y + r1.x + r1.y);
  float a01 = 0.25f * (r0.z + r0.w + r1.z + r1.w);
  float a10 = 0.25f * (r2.x + r2.y + r3.x + r3.y);
  float a11 = 0.25f * (r2.z + r2.w + r3.z + r3.w);
  float* cp = C1 + (size_t)c * 1048576 + (size_t)(2 * Y) * 1024 + 2 * X;
  f2 u; u.x = a00; u.y = a01; *(f2*)cp = u;
  f2 v; v.x = a10; v.y = a11; *(f2*)(cp + 1024) = v;
  float m = 0.25f * (a00 + a01 + a10 + a11);
  p2[((size_t)c * 512 + Y) * 512 + X] = m;
  t2[ty][tx] = m;
  __syncthreads();
  int tid = ty * 16 + tx;
  if (tid < 64) {
    int y = tid >> 3, x = tid & 7;
    float w = 0.25f * (t2[2*y][2*x] + t2[2*y][2*x+1] + t2[2*y+1][2*x] + t2[2*y+1][2*x+1]);
    p3[((size_t)c * 256 + blockIdx.y * 8 + y) * 256 + blockIdx.x * 8 + x] = w;
    t3[y][x] = w;
  }
  __syncthreads();
  if (tid < 16) {
    int y = tid >> 2, x = tid & 3;
    float w = 0.25f * (t3[2*y][2*x] + t3[2*y][2*x+1] + t3[2*y+1][2*x] + t3[2*y+1][2*x+1]);
    p4[((size_t)c * 128 + blockIdx.y * 4 + y) * 128 + blockIdx.x * 4 + x] = w;
    t4a[y][x] = w;
  }
  __syncthreads();
  if (tid < 4) {
    int y = tid >> 1, x = tid & 1;
    float w = 0.25f * (t4a[2*y][2*x] + t4a[2*y][2*x+1] + t4a[2*y+1][2*x] + t4a[2*y+1][2*x+1]);
    p5[((size_t)c * 64 + blockIdx.y * 2 + y) * 64 + blockIdx.x * 2 + x] = w;
  }
}

// ---------------- K2: fused up-chains p3->U3, p4->U4, p5->U5 (512^2) --------
__device__ __forceinline__ void up_coords(int o, int n, int& i0, int& i1, float& w0) {
  int m = o >> 1;
  if (o & 1) { i0 = m; i1 = min(m + 1, n - 1); w0 = 0.75f; }
  else       { i0 = max(m - 1, 0); i1 = m;     w0 = 0.25f; }
}

__global__ __launch_bounds__(1024) void upchain_k(const float* __restrict__ p3,
                                                  const float* __restrict__ p4,
                                                  const float* __restrict__ p5,
                                                  float* __restrict__ U3,
                                                  float* __restrict__ U4,
                                                  float* __restrict__ U5) {
  __shared__ float a[19][20];
  __shared__ float mid[34][35];
  int z = blockIdx.z, im = z / 3, ch = z - im * 3;   // grid (8,8,9); 1024 thr
  int X0 = blockIdx.x * 64, Y0 = blockIdx.y * 64;
  int tid = threadIdx.x;
  int bx1 = X0 / 4 - 1, by1 = Y0 / 4 - 1;
  int bx2 = X0 / 2 - 1, by2 = Y0 / 2 - 1;

  if (im == 2) {
    const float* s = p5 + ch * 4096;
    for (int j = tid; j < 18 * 18; j += 1024) {
      int r = j / 18, cc = j % 18;
      int gy = min(max(by1 + r, 0), 127), gx = min(max(bx1 + cc, 0), 127);
      int r0, r1, c0, c1; float wy0, wx0;
      up_coords(gy, 64, r0, r1, wy0);
      up_coords(gx, 64, c0, c1, wx0);
      float wy1 = 1.f - wy0, wx1 = 1.f - wx0;
      a[r][cc] = wy0 * (wx0 * s[r0*64+c0] + wx1 * s[r0*64+c1])
               + wy1 * (wx0 * s[r1*64+c0] + wx1 * s[r1*64+c1]);
    }
    __syncthreads();
    for (int j = tid; j < 34 * 34; j += 1024) {
      int r = j / 34, cc = j % 34;
      int gy = min(max(by2 + r, 0), 255), gx = min(max(bx2 + cc, 0), 255);
      int r0, r1, c0, c1; float wy0, wx0;
      up_coords(gy, 128, r0, r1, wy0);
      up_coords(gx, 128, c0, c1, wx0);
      float wy1 = 1.f - wy0, wx1 = 1.f - wx0;
      int a0 = r0 - by1, a1 = r1 - by1, b0 = c0 - bx1, b1 = c1 - bx1;
      mid[r][cc] = wy0 * (wx0 * a[a0][b0] + wx1 * a[a0][b1])
                 + wy1 * (wx0 * a[a1][b0] + wx1 * a[a1][b1]);
    }
    __syncthreads();
  } else if (im == 1) {
    const float* s = p4 + ch * 16384;
    for (int j = tid; j < 34 * 34; j += 1024) {
      int r = j / 34, cc = j % 34;
      int gy = min(max(by2 + r, 0), 255), gx = min(max(bx2 + cc, 0), 255);
      int r0, r1, c0, c1; float wy0, wx0;
      up_coords(gy, 128, r0, r1, wy0);
      up_coords(gx, 128, c0, c1, wx0);
      float wy1 = 1.f - wy0, wx1 = 1.f - wx0;
      mid[r][cc] = wy0 * (wx0 * s[r0*128+c0] + wx1 * s[r0*128+c1])
                 + wy1 * (wx0 * s[r1*128+c0] + wx1 * s[r1*128+c1]);
    }
    __syncthreads();
  }

  float* dst = (im == 0) ? U3 : (im == 1) ? U4 : U5;
  const float* p3g = p3 + ch * 65536;
  int lx = tid & 63, lyb = tid >> 6;     // lyb 0..15
#pragma unroll
  for (int rr = 0; rr < 4; ++rr) {
    int ly = lyb * 4 + rr;
    int x = X0 + lx, y = Y0 + ly;
    int r0, r1, c0, c1; float wy0, wx0;
    up_coords(y, 256, r0, r1, wy0);
    up_coords(x, 256, c0, c1, wx0);
    float wy1 = 1.f - wy0, wx1 = 1.f - wx0;
    float v;
    if (im == 0) {
      v = wy0 * (wx0 * p3g[r0*256+c0] + wx1 * p3g[r0*256+c1])
        + wy1 * (wx0 * p3g[r1*256+c0] + wx1 * p3g[r1*256+c1]);
    } else {
      int a0 = r0 - by2, a1 = r1 - by2, b0 = c0 - bx2, b1 = c1 - bx2;
      v = wy0 * (wx0 * mid[a0][b0] + wx1 * mid[a0][b1])
        + wy1 * (wx0 * mid[a1][b0] + wx1 * mid[a1][b1]);
    }
    dst[((size_t)ch * 512 + y) * 512 + x] = v;
  }
}

// ---------------- single-channel samplers -----------------------------------
__device__ __forceinline__ void s2c(const float* __restrict__ b, int x0, int y0,
                                    const BP& bp, float o[2][4]) {
  int t = x0 >> 2, ky = y0 >> 2, yph = y0 & 3;
  int c[3], r[3];
#pragma unroll
  for (int j = 0; j < 3; ++j) {
    c[j] = min(max(t - 1 + j, 0), 511);
    r[j] = min(max(ky - 1 + j, 0), 511);
  }
  float v[3][3];
#pragma unroll
  for (int j = 0; j < 3; ++j) {
    const float* row = b + r[j] * 512;
    v[j][0] = row[c[0]]; v[j][1] = row[c[1]]; v[j][2] = row[c[2]];
  }
  const float* wr0 = bp.P[yph];
  const float* wr1 = bp.P[yph + 1];
  float rv0[3], rv1[3];
#pragma unroll
  for (int i = 0; i < 3; ++i) {
    rv0[i] = wr0[0] * v[0][i] + wr0[1] * v[1][i] + wr0[2] * v[2][i];
    rv1[i] = wr1[0] * v[0][i] + wr1[1] * v[1][i] + wr1[2] * v[2][i];
  }
#pragma unroll
  for (int p = 0; p < 4; ++p) {
    o[0][p] = bp.P[p][0] * rv0[0] + bp.P[p][1] * rv0[1] + bp.P[p][2] * rv0[2];
    o[1][p] = bp.P[p][0] * rv1[0] + bp.P[p][1] * rv1[1] + bp.P[p][2] * rv1[2];
  }
}

__device__ __forceinline__ void s1c(const float* __restrict__ b, int x0, int y0,
                                    float o[2][4]) {
  int q0 = x0 >> 1, qy = y0 >> 1;
  int c[4], r[3];
#pragma unroll
  for (int i = 0; i < 4; ++i) c[i] = min(max(q0 - 1 + i, 0), 1023);
#pragma unroll
  for (int j = 0; j < 3; ++j) r[j] = min(max(qy - 1 + j, 0), 1023);
  float v[3][4];
#pragma unroll
  for (int j = 0; j < 3; ++j) {
    const float* row = b + r[j] * 1024;
    v[j][0] = row[c[0]]; v[j][1] = row[c[1]]; v[j][2] = row[c[2]]; v[j][3] = row[c[3]];
  }
  float rv0[4], rv1[4];
#pragma unroll
  for (int i = 0; i < 4; ++i) {
    rv0[i] = 0.25f * v[0][i] + 0.75f * v[1][i];
    rv1[i] = 0.75f * v[1][i] + 0.25f * v[2][i];
  }
  o[0][0] = 0.25f * rv0[0] + 0.75f * rv0[1];
  o[0][1] = 0.75f * rv0[1] + 0.25f * rv0[2];
  o[0][2] = 0.25f * rv0[1] + 0.75f * rv0[2];
  o[0][3] = 0.75f * rv0[2] + 0.25f * rv0[3];
  o[1][0] = 0.25f * rv1[0] + 0.75f * rv1[1];
  o[1][1] = 0.75f * rv1[1] + 0.25f * rv1[2];
  o[1][2] = 0.25f * rv1[1] + 0.75f * rv1[2];
  o[1][3] = 0.75f * rv1[2] + 0.25f * rv1[3];
}

__device__ __forceinline__ void sample_level(int l, int x0, int y0,
    const float* __restrict__ imgc, const float* __restrict__ C1c,
    const float* __restrict__ b2, const float* __restrict__ b3,
    const float* __restrict__ b4, const float* __restrict__ b5,
    const BP& bp, float o[2][4]) {
  if (l == 0) {
    f4 v0 = *(const f4*)(imgc + (size_t)y0 * 2048 + x0);
    f4 v1 = *(const f4*)(imgc + (size_t)(y0 + 1) * 2048 + x0);
    o[0][0] = v0.x; o[0][1] = v0.y; o[0][2] = v0.z; o[0][3] = v0.w;
    o[1][0] = v1.x; o[1][1] = v1.y; o[1][2] = v1.z; o[1][3] = v1.w;
  } else if (l == 1) {
    s1c(C1c, x0, y0, o);
  } else {
    const float* b = (l == 2) ? b2 : (l == 3) ? b3 : (l == 4) ? b4 : b5;
    s2c(b, x0, y0, bp, o);
  }
}

// ---------------- K3: fused classify + blend, one CHANNEL PER WAVE ----------
// block (64,12): ty%3 = channel (uniform within a wave), ty/3 = span row.
// 3x the waves of the fully-fused version -> latency hiding for the stencil
// loads; d2/B arithmetic is recomputed per channel (VALU pipe was idle).
// Ts identity: cc[l] = 4*cc[l-1]  =>  Ts[l] = Ts[l-1]^4  => one exp per px.
__global__ __launch_bounds__(768) void fblend_k(
    const float* __restrict__ img, const float* __restrict__ C1,
    const float* __restrict__ B2, const float* __restrict__ B3,
    const float* __restrict__ B4, const float* __restrict__ B5,
    const float* __restrict__ fixs, int nf,
    float* __restrict__ out, BP bp) {
  int xs = blockIdx.x * 64 + threadIdx.x;       // 0..511
  int ty = threadIdx.y;                          // 0..11
  int ch = ty % 3;
  int yp = blockIdx.y * 4 + (ty / 3);            // 0..1023
  int x0 = xs * 4, y0 = yp * 2;
  size_t ob0 = (size_t)y0 * 2048 + x0;
  const float* imgc = img + (size_t)ch * HW2048;
  float* outc = out + (size_t)ch * HW2048;

  // --- per-pixel min squared distance over fixations ---
  float d2[2][4];
#pragma unroll
  for (int j = 0; j < 2; ++j)
#pragma unroll
    for (int i = 0; i < 4; ++i) d2[j][i] = 3.4e38f;
  for (int f = 0; f < nf; ++f) {
    float dx0 = (float)x0 - fixs[2 * f], dy0 = (float)y0 - fixs[2 * f + 1];
#pragma unroll
    for (int j = 0; j < 2; ++j) {
      float dy = dy0 + (float)j, dy2 = dy * dy;
#pragma unroll
      for (int i = 0; i < 4; ++i) {
        float dx = dx0 + (float)i;
        d2[j][i] = fminf(d2[j][i], dx * dx + dy2);
      }
    }
  }

  // --- span extremes -> lmin / lmax (level is monotone in d^2) ---
  float dmn = d2[0][0], dmx = d2[0][0];
#pragma unroll
  for (int j = 0; j < 2; ++j)
#pragma unroll
    for (int i = 0; i < 4; ++i) {
      dmn = fminf(dmn, d2[j][i]);
      dmx = fmaxf(dmx, d2[j][i]);
    }
  int lmax = (dmx >= bp.D2[0]) + (dmx >= bp.D2[1]) + (dmx >= bp.D2[2]) +
             (dmx >= bp.D2[3]) + (dmx >= bp.D2[4]);

  if (lmax == 0) {   // whole span is As[0] = img
    f4 v0 = *(const f4*)(imgc + ob0);
    f4 v1 = *(const f4*)(imgc + ob0 + 2048);
    __builtin_nontemporal_store(v0, (f4*)(outc + ob0));
    __builtin_nontemporal_store(v1, (f4*)(outc + ob0 + 2048));
    return;
  }

  int lmin = (dmn >= bp.D2[0]) + (dmn >= bp.D2[1]) + (dmn >= bp.D2[2]) +
             (dmn >= bp.D2[3]) + (dmn >= bp.D2[4]);
  bool mixed = (lmin != lmax);

  float thr  = (lmax == 1) ? bp.D2[0] : (lmax == 2) ? bp.D2[1] :
               (lmax == 3) ? bp.D2[2] : (lmax == 4) ? bp.D2[3] : bp.D2[4];
  float cm_A = (lmax == 1) ? bp.cc[0] : (lmax == 2) ? bp.cc[1] :
               (lmax == 3) ? bp.cc[2] : (lmax == 4) ? bp.cc[3] : bp.cc[4];
  float cm_B = (lmax <= 2) ? bp.cc[0] : (lmax == 3) ? bp.cc[1] :
               (lmax == 4) ? bp.cc[2] : bp.cc[3];
  bool top5 = (lmax >= 5);

  // --- per-pixel B + top-level flag ---
  float Bv[2][4];
  bool  tp[2][4];
#pragma unroll
  for (int j = 0; j < 2; ++j)
#pragma unroll
    for (int i = 0; i < 4; ++i) {
      float dd = d2[j][i];
      bool top = (dd >= thr);            // l(px) == lmax
      tp[j][i] = top;
      float d = sqrtf(dd);
      float R = 18.75f / (d + 18.75f);
      float R2 = R * R;
      float cm = top ? cm_A : cm_B;
      float tsm = __expf(-cm * R2);      // Ts[l-1]
      float t2 = tsm * tsm;
      float tsL = (top && top5) ? 0.f : t2 * t2;   // Ts[l] = Ts[l-1]^4
      float B = (0.5f - tsL) / (tsm - tsL + 1e-5f);
      if (!top && lmax == 1) B = 0.f;    // l(px) == 0 pixels: pure img
      Bv[j][i] = B;
    }

  // --- this wave's channel: sample + blend ---
  const float* C1c = C1 + (size_t)ch * 1048576;
  const float* b2  = B2 + (size_t)ch * 262144;
  const float* b3  = B3 + (size_t)ch * 262144;
  const float* b4  = B4 + (size_t)ch * 262144;
  const float* b5  = B5 + (size_t)ch * 262144;

  float sA[2][4];   // sample(lmax)
  float sB[2][4];   // sample(lmax-1)
  float sC[2][4];   // sample(lmax-2) for mixed spans
  sample_level(lmax,     x0, y0, imgc, C1c, b2, b3, b4, b5, bp, sA);
  sample_level(lmax - 1, x0, y0, imgc, C1c, b2, b3, b4, b5, bp, sB);
#pragma unroll
  for (int j = 0; j < 2; ++j)
#pragma unroll
    for (int i = 0; i < 4; ++i) sC[j][i] = sB[j][i];
  if (mixed && lmax >= 2)
    sample_level(lmax - 2, x0, y0, imgc, C1c, b2, b3, b4, b5, bp, sC);
  // (mixed with lmax==1: lmin==0 pixels have B==0, so lo is unused)

  float res[2][4];
#pragma unroll
  for (int j = 0; j < 2; ++j)
#pragma unroll
    for (int i = 0; i < 4; ++i) {
      float B = Bv[j][i];
      bool top = tp[j][i];
      float hi = top ? sA[j][i] : sB[j][i];
      float lo = top ? sB[j][i] : sC[j][i];
      res[j][i] = B * lo + (1.f - B) * hi;
    }

  f4 v0, v1;
  v0.x = res[0][0]; v0.y = res[0][1]; v0.z = res[0][2]; v0.w = res[0][3];
  v1.x = res[1][0]; v1.y = res[1][1]; v1.z = res[1][2]; v1.w = res[1][3];
  __builtin_nontemporal_store(v0, (f4*)(outc + ob0));
  __builtin_nontemporal_store(v1, (f4*)(outc + ob0 + 2048));
}

extern "C" void kernel_launch(void* const* d_in, const int* in_sizes, int n_in,
                              void* d_out, int out_size, void* d_ws, size_t ws_size,
                              hipStream_t stream) {
  const float* img  = (const float*)d_in[0];
  const float* fixs = (const float*)d_in[1];
  int nf = in_sizes[1] / 2;
  float* out = (float*)d_out;
  float* ws  = (float*)d_ws;

  BP bp;
  const double sig = 0.248, Kd = 3.0, Pd = 7.5, Ad = 2.5;
  double obv = sqrt(log(2.0) / Kd) * sig;
  for (int j = 0; j < 5; ++j) {
    double om = obv * pow(2.0, 2 - j);
    double Dj = Pd * Ad * (1.0 / om - 1.0);
    bp.D2[j] = (float)(Dj * Dj);
  }
  for (int X = 0; X < 5; ++X)
    bp.cc[X] = (float)(Kd * pow(2.0, 2.0 * (X - 2)) / (sig * sig));
  const float Pt[4][3] = {{0.375f, 0.625f, 0.f},
                          {0.1875f, 0.75f, 0.0625f},
                          {0.0625f, 0.75f, 0.1875f},
                          {0.f, 0.625f, 0.375f}};
  for (int a = 0; a < 4; ++a) for (int t = 0; t < 3; ++t) bp.P[a][t] = Pt[a][t];

  size_t o = 0;
  float* C1 = ws + o; o += 3ull * 1024 * 1024;
  float* p2 = ws + o; o += 3ull * 512 * 512;
  float* p3 = ws + o; o += 3ull * 256 * 256;
  float* p4 = ws + o; o += 3ull * 128 * 128;
  float* p5 = ws + o; o += 3ull * 64 * 64;
  float* U3 = ws + o; o += 3ull * 512 * 512;
  float* U4 = ws + o; o += 3ull * 512 * 512;
  float* U5 = ws + o; o += 3ull * 512 * 512;

  downAll_k <<<dim3(32, 32, 3), dim3(16, 16), 0, stream>>>(img, C1, p2, p3, p4, p5);
  upchain_k <<<dim3(8, 8, 9),   dim3(1024),   0, stream>>>(p3, p4, p5, U3, U4, U5);
  fblend_k  <<<dim3(8, 256),    dim3(64, 12), 0, stream>>>(img, C1, p2, U3, U4, U5,
                                                           fixs, nf, out, bp);
}

// Round 4
// 131.094 us; speedup vs baseline: 1.0780x; 1.0780x over previous
//
#include <hip/hip_runtime.h>
#include <math.h>

#define HW2048 (2048ull*2048ull)
typedef float f4 __attribute__((ext_vector_type(4)));
typedef float f2 __attribute__((ext_vector_type(2)));

struct BP {
  float P[4][3];   // composed 2-stage bilinear phase weights
  float D2[5];     // d^2 thresholds: L = sum(d2 >= D2[j])
  float cc[5];     // Ts exponent coefs (cc[X] = K*4^(X-2)/sig^2; cc[l] = 4*cc[l-1])
};

// ---------------- K1: img -> C1 + full pyramid p2..p5 (block-local) ---------
__global__ __launch_bounds__(256) void downAll_k(const float* __restrict__ img,
                                                 float* __restrict__ C1,
                                                 float* __restrict__ p2,
                                                 float* __restrict__ p3,
                                                 float* __restrict__ p4,
                                                 float* __restrict__ p5) {
  __shared__ float t2[16][17];
  __shared__ float t3[8][9];
  __shared__ float t4a[4][5];
  int tx = threadIdx.x, ty = threadIdx.y;  // (16,16); grid (32,32,3)
  int X = blockIdx.x * 16 + tx;            // 0..511
  int Y = blockIdx.y * 16 + ty;            // 0..511
  int c = blockIdx.z;
  const float* ip = img + (size_t)c * HW2048 + (size_t)(4 * Y) * 2048 + 4 * X;
  f4 r0 = __builtin_nontemporal_load((const f4*)(ip));
  f4 r1 = __builtin_nontemporal_load((const f4*)(ip + 2048));
  f4 r2 = __builtin_nontemporal_load((const f4*)(ip + 4096));
  f4 r3 = __builtin_nontemporal_load((const f4*)(ip + 6144));
  float a00 = 0.25f * (r0.x + r0.y + r1.x + r1.y);
  float a01 = 0.25f * (r0.z + r0.w + r1.z + r1.w);
  float a10 = 0.25f * (r2.x + r2.y + r3.x + r3.y);
  float a11 = 0.25f * (r2.z + r2.w + r3.z + r3.w);
  float* cp = C1 + (size_t)c * 1048576 + (size_t)(2 * Y) * 1024 + 2 * X;
  f2 u; u.x = a00; u.y = a01; *(f2*)cp = u;
  f2 v; v.x = a10; v.y = a11; *(f2*)(cp + 1024) = v;
  float m = 0.25f * (a00 + a01 + a10 + a11);
  p2[((size_t)c * 512 + Y) * 512 + X] = m;
  t2[ty][tx] = m;
  __syncthreads();
  int tid = ty * 16 + tx;
  if (tid < 64) {
    int y = tid >> 3, x = tid & 7;
    float w = 0.25f * (t2[2*y][2*x] + t2[2*y][2*x+1] + t2[2*y+1][2*x] + t2[2*y+1][2*x+1]);
    p3[((size_t)c * 256 + blockIdx.y * 8 + y) * 256 + blockIdx.x * 8 + x] = w;
    t3[y][x] = w;
  }
  __syncthreads();
  if (tid < 16) {
    int y = tid >> 2, x = tid & 3;
    float w = 0.25f * (t3[2*y][2*x] + t3[2*y][2*x+1] + t3[2*y+1][2*x] + t3[2*y+1][2*x+1]);
    p4[((size_t)c * 128 + blockIdx.y * 4 + y) * 128 + blockIdx.x * 4 + x] = w;
    t4a[y][x] = w;
  }
  __syncthreads();
  if (tid < 4) {
    int y = tid >> 1, x = tid & 1;
    float w = 0.25f * (t4a[2*y][2*x] + t4a[2*y][2*x+1] + t4a[2*y+1][2*x] + t4a[2*y+1][2*x+1]);
    p5[((size_t)c * 64 + blockIdx.y * 2 + y) * 64 + blockIdx.x * 2 + x] = w;
  }
}

// ---------------- K2: fused up-chains p3->U3, p4->U4, p5->U5 (512^2) --------
__device__ __forceinline__ void up_coords(int o, int n, int& i0, int& i1, float& w0) {
  int m = o >> 1;
  if (o & 1) { i0 = m; i1 = min(m + 1, n - 1); w0 = 0.75f; }
  else       { i0 = max(m - 1, 0); i1 = m;     w0 = 0.25f; }
}

__global__ __launch_bounds__(1024) void upchain_k(const float* __restrict__ p3,
                                                  const float* __restrict__ p4,
                                                  const float* __restrict__ p5,
                                                  float* __restrict__ U3,
                                                  float* __restrict__ U4,
                                                  float* __restrict__ U5) {
  __shared__ float a[19][20];
  __shared__ float mid[34][35];
  int z = blockIdx.z, im = z / 3, ch = z - im * 3;   // grid (8,8,9); 1024 thr
  int X0 = blockIdx.x * 64, Y0 = blockIdx.y * 64;
  int tid = threadIdx.x;
  int bx1 = X0 / 4 - 1, by1 = Y0 / 4 - 1;
  int bx2 = X0 / 2 - 1, by2 = Y0 / 2 - 1;

  if (im == 2) {
    const float* s = p5 + ch * 4096;
    for (int j = tid; j < 18 * 18; j += 1024) {
      int r = j / 18, cc = j % 18;
      int gy = min(max(by1 + r, 0), 127), gx = min(max(bx1 + cc, 0), 127);
      int r0, r1, c0, c1; float wy0, wx0;
      up_coords(gy, 64, r0, r1, wy0);
      up_coords(gx, 64, c0, c1, wx0);
      float wy1 = 1.f - wy0, wx1 = 1.f - wx0;
      a[r][cc] = wy0 * (wx0 * s[r0*64+c0] + wx1 * s[r0*64+c1])
               + wy1 * (wx0 * s[r1*64+c0] + wx1 * s[r1*64+c1]);
    }
    __syncthreads();
    for (int j = tid; j < 34 * 34; j += 1024) {
      int r = j / 34, cc = j % 34;
      int gy = min(max(by2 + r, 0), 255), gx = min(max(bx2 + cc, 0), 255);
      int r0, r1, c0, c1; float wy0, wx0;
      up_coords(gy, 128, r0, r1, wy0);
      up_coords(gx, 128, c0, c1, wx0);
      float wy1 = 1.f - wy0, wx1 = 1.f - wx0;
      int a0 = r0 - by1, a1 = r1 - by1, b0 = c0 - bx1, b1 = c1 - bx1;
      mid[r][cc] = wy0 * (wx0 * a[a0][b0] + wx1 * a[a0][b1])
                 + wy1 * (wx0 * a[a1][b0] + wx1 * a[a1][b1]);
    }
    __syncthreads();
  } else if (im == 1) {
    const float* s = p4 + ch * 16384;
    for (int j = tid; j < 34 * 34; j += 1024) {
      int r = j / 34, cc = j % 34;
      int gy = min(max(by2 + r, 0), 255), gx = min(max(bx2 + cc, 0), 255);
      int r0, r1, c0, c1; float wy0, wx0;
      up_coords(gy, 128, r0, r1, wy0);
      up_coords(gx, 128, c0, c1, wx0);
      float wy1 = 1.f - wy0, wx1 = 1.f - wx0;
      mid[r][cc] = wy0 * (wx0 * s[r0*128+c0] + wx1 * s[r0*128+c1])
                 + wy1 * (wx0 * s[r1*128+c0] + wx1 * s[r1*128+c1]);
    }
    __syncthreads();
  }

  float* dst = (im == 0) ? U3 : (im == 1) ? U4 : U5;
  const float* p3g = p3 + ch * 65536;
  int lx = tid & 63, lyb = tid >> 6;     // lyb 0..15
#pragma unroll
  for (int rr = 0; rr < 4; ++rr) {
    int ly = lyb * 4 + rr;
    int x = X0 + lx, y = Y0 + ly;
    int r0, r1, c0, c1; float wy0, wx0;
    up_coords(y, 256, r0, r1, wy0);
    up_coords(x, 256, c0, c1, wx0);
    float wy1 = 1.f - wy0, wx1 = 1.f - wx0;
    float v;
    if (im == 0) {
      v = wy0 * (wx0 * p3g[r0*256+c0] + wx1 * p3g[r0*256+c1])
        + wy1 * (wx0 * p3g[r1*256+c0] + wx1 * p3g[r1*256+c1]);
    } else {
      int a0 = r0 - by2, a1 = r1 - by2, b0 = c0 - bx2, b1 = c1 - bx2;
      v = wy0 * (wx0 * mid[a0][b0] + wx1 * mid[a0][b1])
        + wy1 * (wx0 * mid[a1][b0] + wx1 * mid[a1][b1]);
    }
    dst[((size_t)ch * 512 + y) * 512 + x] = v;
  }
}

// ---------------- single-channel samplers -----------------------------------
__device__ __forceinline__ void s2c(const float* __restrict__ b, int x0, int y0,
                                    const BP& bp, float o[2][4]) {
  int t = x0 >> 2, ky = y0 >> 2, yph = y0 & 3;
  int c[3], r[3];
#pragma unroll
  for (int j = 0; j < 3; ++j) {
    c[j] = min(max(t - 1 + j, 0), 511);
    r[j] = min(max(ky - 1 + j, 0), 511);
  }
  float v[3][3];
#pragma unroll
  for (int j = 0; j < 3; ++j) {
    const float* row = b + r[j] * 512;
    v[j][0] = row[c[0]]; v[j][1] = row[c[1]]; v[j][2] = row[c[2]];
  }
  const float* wr0 = bp.P[yph];
  const float* wr1 = bp.P[yph + 1];
  float rv0[3], rv1[3];
#pragma unroll
  for (int i = 0; i < 3; ++i) {
    rv0[i] = wr0[0] * v[0][i] + wr0[1] * v[1][i] + wr0[2] * v[2][i];
    rv1[i] = wr1[0] * v[0][i] + wr1[1] * v[1][i] + wr1[2] * v[2][i];
  }
#pragma unroll
  for (int p = 0; p < 4; ++p) {
    o[0][p] = bp.P[p][0] * rv0[0] + bp.P[p][1] * rv0[1] + bp.P[p][2] * rv0[2];
    o[1][p] = bp.P[p][0] * rv1[0] + bp.P[p][1] * rv1[1] + bp.P[p][2] * rv1[2];
  }
}

__device__ __forceinline__ void s1c(const float* __restrict__ b, int x0, int y0,
                                    float o[2][4]) {
  int q0 = x0 >> 1, qy = y0 >> 1;
  int c[4], r[3];
#pragma unroll
  for (int i = 0; i < 4; ++i) c[i] = min(max(q0 - 1 + i, 0), 1023);
#pragma unroll
  for (int j = 0; j < 3; ++j) r[j] = min(max(qy - 1 + j, 0), 1023);
  float v[3][4];
#pragma unroll
  for (int j = 0; j < 3; ++j) {
    const float* row = b + r[j] * 1024;
    v[j][0] = row[c[0]]; v[j][1] = row[c[1]]; v[j][2] = row[c[2]]; v[j][3] = row[c[3]];
  }
  float rv0[4], rv1[4];
#pragma unroll
  for (int i = 0; i < 4; ++i) {
    rv0[i] = 0.25f * v[0][i] + 0.75f * v[1][i];
    rv1[i] = 0.75f * v[1][i] + 0.25f * v[2][i];
  }
  o[0][0] = 0.25f * rv0[0] + 0.75f * rv0[1];
  o[0][1] = 0.75f * rv0[1] + 0.25f * rv0[2];
  o[0][2] = 0.25f * rv0[1] + 0.75f * rv0[2];
  o[0][3] = 0.75f * rv0[2] + 0.25f * rv0[3];
  o[1][0] = 0.25f * rv1[0] + 0.75f * rv1[1];
  o[1][1] = 0.75f * rv1[1] + 0.25f * rv1[2];
  o[1][2] = 0.25f * rv1[1] + 0.75f * rv1[2];
  o[1][3] = 0.75f * rv1[2] + 0.25f * rv1[3];
}

__device__ __forceinline__ void sample_level(int l, int x0, int y0,
    const float* __restrict__ imgc, const float* __restrict__ C1c,
    const float* __restrict__ b2, const float* __restrict__ b3,
    const float* __restrict__ b4, const float* __restrict__ b5,
    const BP& bp, float o[2][4]) {
  if (l == 0) {
    f4 v0 = *(const f4*)(imgc + (size_t)y0 * 2048 + x0);
    f4 v1 = *(const f4*)(imgc + (size_t)(y0 + 1) * 2048 + x0);
    o[0][0] = v0.x; o[0][1] = v0.y; o[0][2] = v0.z; o[0][3] = v0.w;
    o[1][0] = v1.x; o[1][1] = v1.y; o[1][2] = v1.z; o[1][3] = v1.w;
  } else if (l == 1) {
    s1c(C1c, x0, y0, o);
  } else {
    const float* b = (l == 2) ? b2 : (l == 3) ? b3 : (l == 4) ? b4 : b5;
    s2c(b, x0, y0, bp, o);
  }
}

// ---------------- K3: fused classify + 3-channel blend ----------------------
// One thread = one 4x2 span, ALL 3 channels (d2/B computed once; the R3
// channel-per-wave split tripled the classification VALU and was issue-bound
// at VALUBusy=75%). B math uses v_rsq/v_rcp approximations: ~1ulp into a
// blend weight, vs absmax tolerance 1.0 on 0..255 outputs.
__global__ __launch_bounds__(256) void fblend_k(
    const float* __restrict__ img, const float* __restrict__ C1,
    const float* __restrict__ B2, const float* __restrict__ B3,
    const float* __restrict__ B4, const float* __restrict__ B5,
    const float* __restrict__ fixs, int nf,
    float* __restrict__ out, BP bp) {
  int xs = blockIdx.x * 64 + threadIdx.x;   // 0..511
  int yp = blockIdx.y * 4 + threadIdx.y;    // 0..1023
  int x0 = xs * 4, y0 = yp * 2;
  size_t ob0 = (size_t)y0 * 2048 + x0;

  // --- per-pixel min squared distance over fixations ---
  float d2[2][4];
#pragma unroll
  for (int j = 0; j < 2; ++j)
#pragma unroll
    for (int i = 0; i < 4; ++i) d2[j][i] = 3.4e38f;
  for (int f = 0; f < nf; ++f) {
    float dx0 = (float)x0 - fixs[2 * f], dy0 = (float)y0 - fixs[2 * f + 1];
#pragma unroll
    for (int j = 0; j < 2; ++j) {
      float dy = dy0 + (float)j, dy2 = dy * dy;
#pragma unroll
      for (int i = 0; i < 4; ++i) {
        float dx = dx0 + (float)i;
        d2[j][i] = fminf(d2[j][i], dx * dx + dy2);
      }
    }
  }

  // --- span extremes -> lmin / lmax (level is monotone in d^2) ---
  float dmn = d2[0][0], dmx = d2[0][0];
#pragma unroll
  for (int j = 0; j < 2; ++j)
#pragma unroll
    for (int i = 0; i < 4; ++i) {
      dmn = fminf(dmn, d2[j][i]);
      dmx = fmaxf(dmx, d2[j][i]);
    }
  int lmax = (dmx >= bp.D2[0]) + (dmx >= bp.D2[1]) + (dmx >= bp.D2[2]) +
             (dmx >= bp.D2[3]) + (dmx >= bp.D2[4]);

  if (lmax == 0) {   // whole span is As[0] = img for all channels
#pragma unroll
    for (int ch = 0; ch < 3; ++ch) {
      const float* imgc = img + (size_t)ch * HW2048;
      f4 v0 = *(const f4*)(imgc + ob0);
      f4 v1 = *(const f4*)(imgc + ob0 + 2048);
      __builtin_nontemporal_store(v0, (f4*)(out + (size_t)ch * HW2048 + ob0));
      __builtin_nontemporal_store(v1, (f4*)(out + (size_t)ch * HW2048 + ob0 + 2048));
    }
    return;
  }

  int lmin = (dmn >= bp.D2[0]) + (dmn >= bp.D2[1]) + (dmn >= bp.D2[2]) +
             (dmn >= bp.D2[3]) + (dmn >= bp.D2[4]);
  bool mixed = (lmin != lmax);

  float thr  = (lmax == 1) ? bp.D2[0] : (lmax == 2) ? bp.D2[1] :
               (lmax == 3) ? bp.D2[2] : (lmax == 4) ? bp.D2[3] : bp.D2[4];
  float cm_A = (lmax == 1) ? bp.cc[0] : (lmax == 2) ? bp.cc[1] :
               (lmax == 3) ? bp.cc[2] : (lmax == 4) ? bp.cc[3] : bp.cc[4];
  float cm_B = (lmax <= 2) ? bp.cc[0] : (lmax == 3) ? bp.cc[1] :
               (lmax == 4) ? bp.cc[2] : bp.cc[3];
  bool top5 = (lmax >= 5);

  // --- per-pixel B (fast-math) + top-level flag; shared by all channels ---
  float Bv[2][4];
  bool  tp[2][4];
#pragma unroll
  for (int j = 0; j < 2; ++j)
#pragma unroll
    for (int i = 0; i < 4; ++i) {
      float dd = d2[j][i];
      bool top = (dd >= thr);            // l(px) == lmax
      tp[j][i] = top;
      float d = dd * __frsqrt_rn(dd);    // sqrt(dd) via v_rsq + mul
      float R = 18.75f * __frcp_rn(d + 18.75f);
      float R2 = R * R;
      float cm = top ? cm_A : cm_B;
      float tsm = __expf(-cm * R2);      // Ts[l-1]
      float t2 = tsm * tsm;
      float tsL = (top && top5) ? 0.f : t2 * t2;   // Ts[l] = Ts[l-1]^4
      float B = (0.5f - tsL) * __frcp_rn(tsm - tsL + 1e-5f);
      if (!top && lmax == 1) B = 0.f;    // l(px)==0: pure img (also guards dd=0)
      Bv[j][i] = B;
    }

  // --- per-channel sampling + blend ---
#pragma unroll
  for (int ch = 0; ch < 3; ++ch) {
    const float* imgc = img + (size_t)ch * HW2048;
    const float* C1c  = C1 + (size_t)ch * 1048576;
    const float* b2   = B2 + (size_t)ch * 262144;
    const float* b3   = B3 + (size_t)ch * 262144;
    const float* b4   = B4 + (size_t)ch * 262144;
    const float* b5   = B5 + (size_t)ch * 262144;

    float sA[2][4];   // sample(lmax)
    float sB[2][4];   // sample(lmax-1)
    float sC[2][4];   // sample(lmax-2) for mixed spans
    sample_level(lmax,     x0, y0, imgc, C1c, b2, b3, b4, b5, bp, sA);
    sample_level(lmax - 1, x0, y0, imgc, C1c, b2, b3, b4, b5, bp, sB);
#pragma unroll
    for (int j = 0; j < 2; ++j)
#pragma unroll
      for (int i = 0; i < 4; ++i) sC[j][i] = sB[j][i];
    if (mixed && lmax >= 2)
      sample_level(lmax - 2, x0, y0, imgc, C1c, b2, b3, b4, b5, bp, sC);
    // (mixed with lmax==1: lmin==0 pixels have B==0, so lo is unused)

    float res[2][4];
#pragma unroll
    for (int j = 0; j < 2; ++j)
#pragma unroll
      for (int i = 0; i < 4; ++i) {
        float B = Bv[j][i];
        bool top = tp[j][i];
        float hi = top ? sA[j][i] : sB[j][i];
        float lo = top ? sB[j][i] : sC[j][i];
        res[j][i] = B * lo + (1.f - B) * hi;
      }

    f4 v0, v1;
    v0.x = res[0][0]; v0.y = res[0][1]; v0.z = res[0][2]; v0.w = res[0][3];
    v1.x = res[1][0]; v1.y = res[1][1]; v1.z = res[1][2]; v1.w = res[1][3];
    __builtin_nontemporal_store(v0, (f4*)(out + (size_t)ch * HW2048 + ob0));
    __builtin_nontemporal_store(v1, (f4*)(out + (size_t)ch * HW2048 + ob0 + 2048));
  }
}

extern "C" void kernel_launch(void* const* d_in, const int* in_sizes, int n_in,
                              void* d_out, int out_size, void* d_ws, size_t ws_size,
                              hipStream_t stream) {
  const float* img  = (const float*)d_in[0];
  const float* fixs = (const float*)d_in[1];
  int nf = in_sizes[1] / 2;
  float* out = (float*)d_out;
  float* ws  = (float*)d_ws;

  BP bp;
  const double sig = 0.248, Kd = 3.0, Pd = 7.5, Ad = 2.5;
  double obv = sqrt(log(2.0) / Kd) * sig;
  for (int j = 0; j < 5; ++j) {
    double om = obv * pow(2.0, 2 - j);
    double Dj = Pd * Ad * (1.0 / om - 1.0);
    bp.D2[j] = (float)(Dj * Dj);
  }
  for (int X = 0; X < 5; ++X)
    bp.cc[X] = (float)(Kd * pow(2.0, 2.0 * (X - 2)) / (sig * sig));
  const float Pt[4][3] = {{0.375f, 0.625f, 0.f},
                          {0.1875f, 0.75f, 0.0625f},
                          {0.0625f, 0.75f, 0.1875f},
                          {0.f, 0.625f, 0.375f}};
  for (int a = 0; a < 4; ++a) for (int t = 0; t < 3; ++t) bp.P[a][t] = Pt[a][t];

  size_t o = 0;
  float* C1 = ws + o; o += 3ull * 1024 * 1024;
  float* p2 = ws + o; o += 3ull * 512 * 512;
  float* p3 = ws + o; o += 3ull * 256 * 256;
  float* p4 = ws + o; o += 3ull * 128 * 128;
  float* p5 = ws + o; o += 3ull * 64 * 64;
  float* U3 = ws + o; o += 3ull * 512 * 512;
  float* U4 = ws + o; o += 3ull * 512 * 512;
  float* U5 = ws + o; o += 3ull * 512 * 512;

  downAll_k <<<dim3(32, 32, 3), dim3(16, 16), 0, stream>>>(img, C1, p2, p3, p4, p5);
  upchain_k <<<dim3(8, 8, 9),   dim3(1024),   0, stream>>>(p3, p4, p5, U3, U4, U5);
  fblend_k  <<<dim3(8, 256),    dim3(64, 4),  0, stream>>>(img, C1, p2, U3, U4, U5,
                                                           fixs, nf, out, bp);
}